// Round 6
// baseline (871.430 us; speedup 1.0000x reference)
//
#include <hip/hip_runtime.h>

// HT model: exact 3-way bf16 split (x = h+m+l, 3x8=24 mantissa bits) + MFMA.
// 8 of 9 cross products (drop l*l <= 2^-32) on v_mfma_f32_32x32x16_bf16,
// single fp32 accumulator (verified: absmax identical to fp32-VALU chain).
//
// r6: W-operand fragments are read global->VGPR directly (pre-split planes
// are stored in exact MFMA fragment order, so a frag load is one coalesced
// 1KB dwordx4 per wave, L1/L2-hot) -- removes half the LDS-pipe traffic that
// capped r5 at 35% MfmaUtil. LDS holds only the activation planes (24 KB),
// double-buffered (48 KB, 3 blocks/CU) with one barrier per k-step and
// global loads for k+32 issued before compute on k. ws >= 185 MB.

typedef short short8 __attribute__((ext_vector_type(8)));
typedef float floatx16 __attribute__((ext_vector_type(16)));

__device__ __forceinline__ unsigned bf16_rne(float x) {
    unsigned u = __float_as_uint(x);
    return (u + 0x7FFFu + ((u >> 16) & 1u)) >> 16;
}
__device__ __forceinline__ float bf16_f(unsigned h) { return __uint_as_float(h << 16); }
__device__ __forceinline__ void split3(float x, unsigned& h, unsigned& m, unsigned& l) {
    h = bf16_rne(x);
    float r1 = x - bf16_f(h);      // exact (Sterbenz)
    m = bf16_rne(r1);
    float r2 = r1 - bf16_f(m);     // exact
    l = bf16_rne(r2);
}

// ---------------- weight pre-split into fragment-ordered bf16 planes ----------------
// frag = ((z*3+p)*(K/16) + kc)*NGTtot + (g>>5), 512 shorts per frag;
// slot within frag = ((g&31) | ((k8&1)<<5)) * 8 shorts (16B granule).
struct Seg { const float* src; long dst; int Z, G, Gpad, K, trans, blk0; };
struct SegTable { Seg s[11]; };

__global__ __launch_bounds__(256) void presplit(SegTable T, unsigned short* P) {
    int blk = blockIdx.x;
    int si = 0;
#pragma unroll
    for (int i = 1; i < 11; ++i) if (blk >= T.s[i].blk0) si = i;
    Seg d = T.s[si];
    const int K8 = d.K >> 3;
    long total = (long)d.Z * d.Gpad * K8;
    long o = (long)(blk - d.blk0) * 256 + threadIdx.x;
    if (o >= total) return;
    int k8 = (int)(o % K8);
    long rem = o / K8;
    int g = (int)(rem % d.Gpad);
    int z = (int)(rem / d.Gpad);
    float e[8];
    if (g < d.G) {
        if (!d.trans) {
            const float* s = d.src + ((long)z * d.G + g) * d.K + k8 * 8;
            float4 a = *(const float4*)s, b = *(const float4*)(s + 4);
            e[0]=a.x; e[1]=a.y; e[2]=a.z; e[3]=a.w; e[4]=b.x; e[5]=b.y; e[6]=b.z; e[7]=b.w;
        } else {
#pragma unroll
            for (int i = 0; i < 8; ++i) e[i] = d.src[(long)(k8 * 8 + i) * d.G + g];
        }
    } else {
#pragma unroll
        for (int i = 0; i < 8; ++i) e[i] = 0.f;
    }
    unsigned h[8], m[8], l[8];
#pragma unroll
    for (int i = 0; i < 8; ++i) split3(e[i], h[i], m[i], l[i]);
    uint4 Pp[3];
    Pp[0] = { h[0]|(h[1]<<16), h[2]|(h[3]<<16), h[4]|(h[5]<<16), h[6]|(h[7]<<16) };
    Pp[1] = { m[0]|(m[1]<<16), m[2]|(m[3]<<16), m[4]|(m[5]<<16), m[6]|(m[7]<<16) };
    Pp[2] = { l[0]|(l[1]<<16), l[2]|(l[3]<<16), l[4]|(l[5]<<16), l[6]|(l[7]<<16) };
    const int NGTt = d.Gpad >> 5;
    const int KC16 = d.K >> 4;
    const long slot = (long)((g & 31) | ((k8 & 1) << 5)) * 8;
#pragma unroll
    for (int p = 0; p < 3; ++p) {
        long frag = ((long)(z * 3 + p) * KC16 + (k8 >> 1)) * NGTt + (g >> 5);
        *(uint4*)&P[d.dst + frag * 512 + slot] = Pp[p];
    }
}

// ---------------- main GEMM: C[z][b][g] = sum_k W[z][g][k] * Act[z][b][k] ----------------
template<int GTW, int GWAVES, int DB, int PAIR>
__global__ __launch_bounds__(256, 3) void ht_mfma(
    const float* __restrict__ Act,
    const unsigned short* __restrict__ Wp,   // level plane base (frag-ordered)
    const float* __restrict__ bias,
    float* __restrict__ C,
    int K, int Gtot, int NGTtot,
    long act_z, long act_pair, int act_rb,
    long c_z, int c_rb, int relu)
{
    constexpr int BWAVES = 4 / GWAVES;
    constexpr int BB   = BWAVES * 64;
    constexpr int GG   = GWAVES * GTW * 32;
    constexpr int NBT  = BB / 32;
    constexpr int NR   = BB / 64;
    constexpr int NBUF = DB ? 2 : 1;

    __shared__ unsigned short AS[NBUF][3 * NBT * 1024];

    const int tid  = threadIdx.x;
    const int lane = tid & 63;
    const int w    = tid >> 6;
    const int bw   = w % BWAVES;
    const int gw   = w / BWAVES;

    const int b0  = blockIdx.x * BB;
    const int g0t = blockIdx.y * (GG / 32);
    const int g0  = blockIdx.y * GG;
    const int z   = blockIdx.z;

    const float* Abase = Act + (long)z * act_z + (long)b0 * act_rb;
    const int aslot = ((lane & 31) * 2 + (lane >> 5)) * 8;
    const unsigned short* Wl = Wp + lane * 8;
    const int KC16 = K >> 4;

    float4 va[NR], vb[NR], pa[NR], pb[NR];

    auto issue_loads = [&](int k0) {
#pragma unroll
        for (int r = 0; r < NR; ++r) {
            const int s = r * 256 + tid;
            const int b = s >> 2, oct = s & 3;
            const float* p = Abase + (long)b * act_rb + k0 + oct * 8;
            va[r] = *(const float4*)p;
            vb[r] = *(const float4*)(p + 4);
            if (PAIR) {
                pa[r] = *(const float4*)(p + act_pair);
                pb[r] = *(const float4*)(p + act_pair + 4);
            }
        }
    };
    auto split_write = [&](int buf) {
#pragma unroll
        for (int r = 0; r < NR; ++r) {
            const int s = r * 256 + tid;
            const int b = s >> 2, oct = s & 3;
            float e[8] = { va[r].x, va[r].y, va[r].z, va[r].w,
                           vb[r].x, vb[r].y, vb[r].z, vb[r].w };
            if (PAIR) {
                float f[8] = { pa[r].x, pa[r].y, pa[r].z, pa[r].w,
                               pb[r].x, pb[r].y, pb[r].z, pb[r].w };
#pragma unroll
                for (int i = 0; i < 8; ++i) e[i] *= f[i];
            }
            unsigned h[8], m[8], l[8];
#pragma unroll
            for (int i = 0; i < 8; ++i) split3(e[i], h[i], m[i], l[i]);
            uint4 Ph = { h[0]|(h[1]<<16), h[2]|(h[3]<<16), h[4]|(h[5]<<16), h[6]|(h[7]<<16) };
            uint4 Pm = { m[0]|(m[1]<<16), m[2]|(m[3]<<16), m[4]|(m[5]<<16), m[6]|(m[7]<<16) };
            uint4 Pl = { l[0]|(l[1]<<16), l[2]|(l[3]<<16), l[4]|(l[5]<<16), l[6]|(l[7]<<16) };
            const int base = (b >> 5) * 1024 + (oct >> 1) * 512 + ((b & 31) * 2 + (oct & 1)) * 8;
            *(uint4*)&AS[buf][base] = Ph;
            *(uint4*)&AS[buf][NBT * 1024 + base] = Pm;
            *(uint4*)&AS[buf][2 * NBT * 1024 + base] = Pl;
        }
    };

    floatx16 acc[2][GTW];
#pragma unroll
    for (int bt = 0; bt < 2; ++bt)
#pragma unroll
        for (int gt = 0; gt < GTW; ++gt) acc[bt][gt] = (floatx16)0.f;

    auto compute = [&](int k0, int buf) {
#pragma unroll
        for (int kc = 0; kc < 2; ++kc) {
            // W fragments: direct global->VGPR (frag-ordered, coalesced, L1/L2-hot)
            short8 wf[3][GTW];
#pragma unroll
            for (int sa = 0; sa < 3; ++sa)
#pragma unroll
                for (int gt = 0; gt < GTW; ++gt) {
                    const long frag = ((long)(z * 3 + sa) * KC16 + (k0 >> 4) + kc) * NGTtot
                                      + g0t + gw * GTW + gt;
                    wf[sa][gt] = *(const short8*)(Wl + frag * 512);
                }
            short8 af[3][2];
#pragma unroll
            for (int sb = 0; sb < 3; ++sb)
#pragma unroll
                for (int bt = 0; bt < 2; ++bt)
                    af[sb][bt] = *(const short8*)&AS[buf][(sb * NBT + bw * 2 + bt) * 1024
                                                         + kc * 512 + aslot];
#pragma unroll
            for (int sa = 0; sa < 3; ++sa) {
                const int nsb = (sa == 2) ? 2 : 3;
#pragma unroll
                for (int gt = 0; gt < GTW; ++gt)
#pragma unroll
                    for (int sb = 0; sb < 3; ++sb) {
                        if (sb >= nsb) continue;
#pragma unroll
                        for (int bt = 0; bt < 2; ++bt)
                            acc[bt][gt] = __builtin_amdgcn_mfma_f32_32x32x16_bf16(
                                wf[sa][gt], af[sb][bt], acc[bt][gt], 0, 0, 0);
                    }
            }
        }
    };

    // prologue: stage k=0
    issue_loads(0);
    split_write(0);
    __syncthreads();

    for (int k0 = 0; k0 < K; k0 += 32) {
        const int cur = DB ? ((k0 >> 5) & 1) : 0;
        const bool more = (k0 + 32 < K);
        if (DB && more) issue_loads(k0 + 32);
        compute(k0, cur);
        if (more) {
            if (DB) {
                split_write(cur ^ 1);
                __syncthreads();
            } else {
                __syncthreads();
                issue_loads(k0 + 32);
                split_write(0);
                __syncthreads();
            }
        }
    }

    // ---- epilogue: D col=lane&31 (b), row=(reg&3)+8*(reg>>2)+4*(lane>>5) (g)
    const int koct = lane >> 5;
#pragma unroll
    for (int bt = 0; bt < 2; ++bt) {
        const int b = b0 + bw * 64 + bt * 32 + (lane & 31);
        float* crow = C + (long)z * c_z + (long)b * c_rb;
#pragma unroll
        for (int gt = 0; gt < GTW; ++gt) {
            const int gb = g0 + gw * (GTW * 32) + gt * 32 + 4 * koct;
#pragma unroll
            for (int r4 = 0; r4 < 4; ++r4) {
                const int g = gb + r4 * 8;
                float4 o;
                o.x = acc[bt][gt][r4 * 4 + 0];
                o.y = acc[bt][gt][r4 * 4 + 1];
                o.z = acc[bt][gt][r4 * 4 + 2];
                o.w = acc[bt][gt][r4 * 4 + 3];
                if (bias) {
                    float4 bv = *(const float4*)(bias + g);
                    o.x += bv.x; o.y += bv.y; o.z += bv.z; o.w += bv.w;
                }
                if (relu) {
                    o.x = fmaxf(o.x, 0.f); o.y = fmaxf(o.y, 0.f);
                    o.z = fmaxf(o.z, 0.f); o.w = fmaxf(o.w, 0.f);
                }
                if (g + 3 < Gtot) {
                    *(float4*)(crow + g) = o;
                } else if (g < Gtot) {
                    crow[g] = o.x;
                    if (g + 1 < Gtot) crow[g + 1] = o.y;
                    if (g + 2 < Gtot) crow[g + 2] = o.z;
                }
            }
        }
    }
}

extern "C" void kernel_launch(void* const* d_in, const int* in_sizes, int n_in,
                              void* d_out, int out_size, void* d_ws, size_t ws_size,
                              hipStream_t stream)
{
    const float* X    = (const float*)d_in[0];
    const float* W1   = (const float*)d_in[1];
    const float* b1   = (const float*)d_in[2];
    const float* W2   = (const float*)d_in[3];
    const float* b2   = (const float*)d_in[4];
    const float* W3   = (const float*)d_in[5];
    const float* b3   = (const float*)d_in[6];
    const float* W4   = (const float*)d_in[7];
    const float* b4   = (const float*)d_in[8];
    const float* P0   = (const float*)d_in[9];
    const float* P1   = (const float*)d_in[10];
    const float* P2   = (const float*)d_in[11];
    const float* P3   = (const float*)d_in[12];
    const float* P4   = (const float*)d_in[13];
    const float* P5   = (const float*)d_in[14];
    const float* Ptop = (const float*)d_in[15];
    float* out = (float*)d_out;

    unsigned short* planes = (unsigned short*)d_ws;
    float* base = (float*)d_ws;
    // planes occupy [0, 6124032) floats; fp32 regions start at 6291456
    float* h1c = base + 6291456L;          // [131072][128]
    float* h2c = base + 23068672L;         // [131072][64]
    float* h3c = base + 6291456L;          // [131072][32] (h1c dead)
    float* Fc  = base + 10485760L;         // [131072][32]
    float* t0  = base + 31457280L;         // [64][4096][64]
    float* t1  = base + 6291456L;          // [32][4096][128]
    float* t2  = base + 23068672L;         // [16][4096][256]
    float* t3  = base + 6291456L;          // [8][4096][512]
    float* t4  = base + 39845888L;         // [4][4096][512]
    float* t5  = base + 23068672L;         // [2][4096][512]

    // ---- pre-split weights (frag-ordered planes)
    SegTable T;
    auto seg = [](const float* s, long dst, int Z, int G, int Gpad, int K, int tr, int b0) {
        Seg d; d.src=s; d.dst=dst; d.Z=Z; d.G=G; d.Gpad=Gpad; d.K=K; d.trans=tr; d.blk0=b0; return d;
    };
    T.s[0]  = seg(W1,   0L,        1, 128, 128,  64, 1, 0);
    T.s[1]  = seg(W2,   24576L,    1,  64,  64, 128, 1, 4);
    T.s[2]  = seg(W3,   49152L,    1,  32,  32,  64, 1, 8);
    T.s[3]  = seg(W4,   55296L,    1,  32,  32,  32, 1, 9);
    T.s[4]  = seg(P0,   58368L,   64,  64,  64,  32, 0, 10);
    T.s[5]  = seg(P1,   451584L,  32, 128, 128,  64, 0, 74);
    T.s[6]  = seg(P2,   1238016L, 16, 256, 256, 128, 0, 202);
    T.s[7]  = seg(P3,   2810880L,  8, 512, 512, 256, 0, 458);
    T.s[8]  = seg(P4,   5956608L,  4, 512, 512, 512, 0, 970);
    T.s[9]  = seg(P5,   9102336L,  2, 512, 512, 512, 0, 1482);
    T.s[10] = seg(Ptop, 10675200L, 1, 1000, 1024, 512, 0, 1738);
    presplit<<<dim3(1994), dim3(256), 0, stream>>>(T, planes);

    dim3 blk(256, 1, 1);

    // ---- MLP + leaf, 2 chunks of 131072 tokens
    for (int c = 0; c < 2; ++c) {
        const float* Xc = X + (long)c * 131072 * 64;
        // mlp1: 64->128 relu   (block 128x128)
        ht_mfma<2, 2, 1, 0><<<dim3(1024, 1, 1), blk, 0, stream>>>(
            Xc, planes + 0, b1, h1c, 64, 128, 4, 0L, 0L, 64, 0L, 128, 1);
        // mlp2: 128->64 relu   (block 128x64)
        ht_mfma<1, 2, 1, 0><<<dim3(1024, 1, 1), blk, 0, stream>>>(
            h1c, planes + 24576, b2, h2c, 128, 64, 2, 0L, 0L, 128, 0L, 64, 1);
        // mlp3: 64->32 relu    (block 256x32)
        ht_mfma<1, 1, 0, 0><<<dim3(512, 1, 1), blk, 0, stream>>>(
            h2c, planes + 49152, b3, h3c, 64, 32, 1, 0L, 0L, 64, 0L, 32, 1);
        // mlp4: 32->32         (block 256x32)
        ht_mfma<1, 1, 0, 0><<<dim3(512, 1, 1), blk, 0, stream>>>(
            h3c, planes + 55296, b4, Fc, 32, 32, 1, 0L, 0L, 32, 0L, 32, 0);
        // leaf: t0[j][b][a] = sum_m P0[j][a][m] * F[(b,j)][m]
        ht_mfma<1, 2, 1, 0><<<dim3(16, 1, 64), blk, 0, stream>>>(
            Fc, planes + 58368, nullptr, t0 + (long)c * 131072, 32, 64, 2,
            32L, 0L, 2048, 262144L, 64, 0);
    }

    // ---- tree: t_l[n][b][g] = sum_a P_l[n][g][a] * t[2n][b][a]*t[2n+1][b][a]
    ht_mfma<2, 2, 1, 1><<<dim3(32, 1, 32), blk, 0, stream>>>(   // L1 K=64 G=128
        t0, planes + 451584, nullptr, t1, 64, 128, 4,
        524288L, 262144L, 64, 524288L, 128, 0);
    ht_mfma<2, 2, 1, 1><<<dim3(32, 2, 16), blk, 0, stream>>>(   // L2 K=128 G=256
        t1, planes + 1238016, nullptr, t2, 128, 256, 8,
        1048576L, 524288L, 128, 1048576L, 256, 0);
    ht_mfma<2, 2, 1, 1><<<dim3(32, 4, 8), blk, 0, stream>>>(    // L3 K=256 G=512
        t2, planes + 2810880, nullptr, t3, 256, 512, 16,
        2097152L, 1048576L, 256, 2097152L, 512, 0);
    ht_mfma<2, 2, 1, 1><<<dim3(32, 4, 4), blk, 0, stream>>>(    // L4 K=512 G=512
        t3, planes + 5956608, nullptr, t4, 512, 512, 16,
        4194304L, 2097152L, 512, 2097152L, 512, 0);
    ht_mfma<1, 2, 1, 1><<<dim3(32, 8, 2), blk, 0, stream>>>(    // L5 K=512 G=512
        t4, planes + 9102336, nullptr, t5, 512, 512, 16,
        4194304L, 2097152L, 512, 2097152L, 512, 0);
    ht_mfma<1, 2, 1, 1><<<dim3(32, 16, 1), blk, 0, stream>>>(   // top K=512 G=1000
        t5, planes + 10675200, nullptr, out, 512, 1000, 32,
        0L, 2097152L, 512, 0L, 1000, 0);
}

// Round 7
// 512.146 us; speedup vs baseline: 1.7015x; 1.7015x over previous
//
#include <hip/hip_runtime.h>

// HT model: exact 2-way bf16 split (x = h + m, ~2^-18 representation error)
// + MFMA. Products keep hh', hm', mh' (drop mm' ~2^-18) on
// v_mfma_f32_32x32x16_bf16, fp32 accumulator. Error after 2^6 tree
// amplification ~1e-38 absolute vs 4.4e-37 threshold (we have large margin:
// absmax was bit-identical across fp32-VALU and 3-way-split engines).
//
// r7: W-operand fragments read global->VGPR (pre-split planes in exact MFMA
// fragment order: 1KB coalesced dwordx4 per wave, L2-hot). LDS holds ONLY the
// two activation planes (8-32 KB), single-buffered. NO registers held across
// compute (r6's spill trap); GTW=4 kernels use launch_bounds(256,2).
// All intermediates fp32, b-major [node][b][k]. ws >= 185 MB.

typedef short short8 __attribute__((ext_vector_type(8)));
typedef float floatx16 __attribute__((ext_vector_type(16)));

__device__ __forceinline__ unsigned bf16_rne(float x) {
    unsigned u = __float_as_uint(x);
    return (u + 0x7FFFu + ((u >> 16) & 1u)) >> 16;
}
__device__ __forceinline__ float bf16_f(unsigned h) { return __uint_as_float(h << 16); }
__device__ __forceinline__ void split2(float x, unsigned& h, unsigned& m) {
    h = bf16_rne(x);
    float r = x - bf16_f(h);       // exact (Sterbenz)
    m = bf16_rne(r);
}

// ---------------- weight pre-split into fragment-ordered bf16 planes ----------------
// frag = ((z*2+p)*(K/16) + k16)*NGTtot + (g>>5), 512 shorts per frag;
// slot within frag = ((g&31) | ((k8&1)<<5)) * 8 shorts (16B granule).
struct Seg { const float* src; long dst; int Z, G, Gpad, K, trans, blk0; };
struct SegTable { Seg s[11]; };

__global__ __launch_bounds__(256) void presplit(SegTable T, unsigned short* P) {
    int blk = blockIdx.x;
    int si = 0;
#pragma unroll
    for (int i = 1; i < 11; ++i) if (blk >= T.s[i].blk0) si = i;
    Seg d = T.s[si];
    const int K8 = d.K >> 3;
    long total = (long)d.Z * d.Gpad * K8;
    long o = (long)(blk - d.blk0) * 256 + threadIdx.x;
    if (o >= total) return;
    int k8 = (int)(o % K8);
    long rem = o / K8;
    int g = (int)(rem % d.Gpad);
    int z = (int)(rem / d.Gpad);
    float e[8];
    if (g < d.G) {
        if (!d.trans) {
            const float* s = d.src + ((long)z * d.G + g) * d.K + k8 * 8;
            float4 a = *(const float4*)s, b = *(const float4*)(s + 4);
            e[0]=a.x; e[1]=a.y; e[2]=a.z; e[3]=a.w; e[4]=b.x; e[5]=b.y; e[6]=b.z; e[7]=b.w;
        } else {
#pragma unroll
            for (int i = 0; i < 8; ++i) e[i] = d.src[(long)(k8 * 8 + i) * d.G + g];
        }
    } else {
#pragma unroll
        for (int i = 0; i < 8; ++i) e[i] = 0.f;
    }
    unsigned h[8], m[8];
#pragma unroll
    for (int i = 0; i < 8; ++i) split2(e[i], h[i], m[i]);
    uint4 Ph = { h[0]|(h[1]<<16), h[2]|(h[3]<<16), h[4]|(h[5]<<16), h[6]|(h[7]<<16) };
    uint4 Pm = { m[0]|(m[1]<<16), m[2]|(m[3]<<16), m[4]|(m[5]<<16), m[6]|(m[7]<<16) };
    const int NGTt = d.Gpad >> 5;
    const int KC16 = d.K >> 4;
    const long slot = (long)((g & 31) | ((k8 & 1) << 5)) * 8;
    long fh = ((long)(z * 2 + 0) * KC16 + (k8 >> 1)) * NGTt + (g >> 5);
    long fm = ((long)(z * 2 + 1) * KC16 + (k8 >> 1)) * NGTt + (g >> 5);
    *(uint4*)&P[d.dst + fh * 512 + slot] = Ph;
    *(uint4*)&P[d.dst + fm * 512 + slot] = Pm;
}

// ---------------- main GEMM: C[z][b][g] = sum_k W[z][g][k] * Act[z][b][k] ----------------
template<int BT, int GTW, int GWAVES, int MINW, int PAIR>
__global__ __launch_bounds__(256, MINW) void ht_mfma(
    const float* __restrict__ Act,
    const unsigned short* __restrict__ Wp,   // level plane base (frag-ordered)
    const float* __restrict__ bias,
    float* __restrict__ C,
    int K, int Gtot, int NGTtot,
    long act_z, long act_pair, int act_rb,
    long c_z, int c_rb, int relu)
{
    constexpr int BWAVES = 4 / GWAVES;
    constexpr int BB  = BWAVES * BT * 32;
    constexpr int GG  = GWAVES * GTW * 32;
    constexpr int NBT = BB / 32;
    constexpr int NR  = BB / 64;

    __shared__ unsigned short AS[2 * NBT * 1024];

    const int tid  = threadIdx.x;
    const int lane = tid & 63;
    const int w    = tid >> 6;
    const int bw   = w % BWAVES;
    const int gw   = w / BWAVES;

    const int b0  = blockIdx.x * BB;
    const int g0t = blockIdx.y * (GG / 32);
    const int g0  = blockIdx.y * GG;
    const int z   = blockIdx.z;

    const float* Abase = Act + (long)z * act_z + (long)b0 * act_rb;
    const int aslot = ((lane & 31) * 2 + (lane >> 5)) * 8;
    const unsigned short* Wl = Wp + lane * 8;
    const int KC16 = K >> 4;

    auto stage = [&](int k0) {
#pragma unroll
        for (int r = 0; r < NR; ++r) {
            const int s = r * 256 + tid;
            const int b = s >> 2, oct = s & 3;
            const float* p = Abase + (long)b * act_rb + k0 + oct * 8;
            float4 v0 = *(const float4*)p;
            float4 v1 = *(const float4*)(p + 4);
            if (PAIR) {
                float4 u0 = *(const float4*)(p + act_pair);
                float4 u1 = *(const float4*)(p + act_pair + 4);
                v0.x *= u0.x; v0.y *= u0.y; v0.z *= u0.z; v0.w *= u0.w;
                v1.x *= u1.x; v1.y *= u1.y; v1.z *= u1.z; v1.w *= u1.w;
            }
            float e[8] = { v0.x, v0.y, v0.z, v0.w, v1.x, v1.y, v1.z, v1.w };
            unsigned h[8], m[8];
#pragma unroll
            for (int i = 0; i < 8; ++i) split2(e[i], h[i], m[i]);
            uint4 Ph = { h[0]|(h[1]<<16), h[2]|(h[3]<<16), h[4]|(h[5]<<16), h[6]|(h[7]<<16) };
            uint4 Pm = { m[0]|(m[1]<<16), m[2]|(m[3]<<16), m[4]|(m[5]<<16), m[6]|(m[7]<<16) };
            const int base = (b >> 5) * 1024 + (oct >> 1) * 512 + ((b & 31) * 2 + (oct & 1)) * 8;
            *(uint4*)&AS[base] = Ph;
            *(uint4*)&AS[NBT * 1024 + base] = Pm;
        }
    };

    floatx16 acc[BT][GTW];
#pragma unroll
    for (int bt = 0; bt < BT; ++bt)
#pragma unroll
        for (int gt = 0; gt < GTW; ++gt) acc[bt][gt] = (floatx16)0.f;

    stage(0);
    __syncthreads();

    for (int k0 = 0; k0 < K; k0 += 32) {
#pragma unroll
        for (int kc = 0; kc < 2; ++kc) {
            // W fragments: direct global->VGPR (frag-ordered, coalesced, L2-hot)
            short8 wf[2][GTW];
#pragma unroll
            for (int sa = 0; sa < 2; ++sa)
#pragma unroll
                for (int gt = 0; gt < GTW; ++gt) {
                    const long frag = ((long)(z * 2 + sa) * KC16 + (k0 >> 4) + kc) * NGTtot
                                      + g0t + gw * GTW + gt;
                    wf[sa][gt] = *(const short8*)(Wl + frag * 512);
                }
            short8 af[2][BT];
#pragma unroll
            for (int sb = 0; sb < 2; ++sb)
#pragma unroll
                for (int bt = 0; bt < BT; ++bt)
                    af[sb][bt] = *(const short8*)&AS[(sb * NBT + bw * BT + bt) * 1024
                                                     + kc * 512 + aslot];
            // products hh, hm, mh (drop mm)
#pragma unroll
            for (int gt = 0; gt < GTW; ++gt) {
#pragma unroll
                for (int bt = 0; bt < BT; ++bt)
                    acc[bt][gt] = __builtin_amdgcn_mfma_f32_32x32x16_bf16(
                        wf[0][gt], af[0][bt], acc[bt][gt], 0, 0, 0);
#pragma unroll
                for (int bt = 0; bt < BT; ++bt)
                    acc[bt][gt] = __builtin_amdgcn_mfma_f32_32x32x16_bf16(
                        wf[0][gt], af[1][bt], acc[bt][gt], 0, 0, 0);
#pragma unroll
                for (int bt = 0; bt < BT; ++bt)
                    acc[bt][gt] = __builtin_amdgcn_mfma_f32_32x32x16_bf16(
                        wf[1][gt], af[0][bt], acc[bt][gt], 0, 0, 0);
            }
        }
        if (k0 + 32 < K) {
            __syncthreads();
            stage(k0 + 32);
            __syncthreads();
        }
    }

    // ---- epilogue: D col=lane&31 (b), row g=(reg&3)+8*(reg>>2)+4*(lane>>5)
    const int koct = lane >> 5;
#pragma unroll
    for (int bt = 0; bt < BT; ++bt) {
        const int b = b0 + bw * (BT * 32) + bt * 32 + (lane & 31);
        float* crow = C + (long)z * c_z + (long)b * c_rb;
#pragma unroll
        for (int gt = 0; gt < GTW; ++gt) {
            const int gb = g0 + gw * (GTW * 32) + gt * 32 + 4 * koct;
#pragma unroll
            for (int r4 = 0; r4 < 4; ++r4) {
                const int g = gb + r4 * 8;
                float4 o;
                o.x = acc[bt][gt][r4 * 4 + 0];
                o.y = acc[bt][gt][r4 * 4 + 1];
                o.z = acc[bt][gt][r4 * 4 + 2];
                o.w = acc[bt][gt][r4 * 4 + 3];
                if (bias) {
                    float4 bv = *(const float4*)(bias + g);
                    o.x += bv.x; o.y += bv.y; o.z += bv.z; o.w += bv.w;
                }
                if (relu) {
                    o.x = fmaxf(o.x, 0.f); o.y = fmaxf(o.y, 0.f);
                    o.z = fmaxf(o.z, 0.f); o.w = fmaxf(o.w, 0.f);
                }
                if (g + 3 < Gtot) {
                    *(float4*)(crow + g) = o;
                } else if (g < Gtot) {
                    crow[g] = o.x;
                    if (g + 1 < Gtot) crow[g + 1] = o.y;
                    if (g + 2 < Gtot) crow[g + 2] = o.z;
                }
            }
        }
    }
}

extern "C" void kernel_launch(void* const* d_in, const int* in_sizes, int n_in,
                              void* d_out, int out_size, void* d_ws, size_t ws_size,
                              hipStream_t stream)
{
    const float* X    = (const float*)d_in[0];
    const float* W1   = (const float*)d_in[1];
    const float* b1   = (const float*)d_in[2];
    const float* W2   = (const float*)d_in[3];
    const float* b2   = (const float*)d_in[4];
    const float* W3   = (const float*)d_in[5];
    const float* b3   = (const float*)d_in[6];
    const float* W4   = (const float*)d_in[7];
    const float* b4   = (const float*)d_in[8];
    const float* P0   = (const float*)d_in[9];
    const float* P1   = (const float*)d_in[10];
    const float* P2   = (const float*)d_in[11];
    const float* P3   = (const float*)d_in[12];
    const float* P4   = (const float*)d_in[13];
    const float* P5   = (const float*)d_in[14];
    const float* Ptop = (const float*)d_in[15];
    float* out = (float*)d_out;

    unsigned short* planes = (unsigned short*)d_ws;
    float* base = (float*)d_ws;
    // planes occupy [0, 8165376) shorts = 4082688 floats; fp32 region >= 6291456
    float* h1c = base + 6291456L;          // [131072][128]
    float* h2c = base + 23068672L;         // [131072][64]
    float* h3c = base + 6291456L;          // [131072][32] (h1c dead)
    float* Fc  = base + 10485760L;         // [131072][32]
    float* t0  = base + 31457280L;         // [64][4096][64]
    float* t1  = base + 6291456L;          // [32][4096][128]
    float* t2  = base + 23068672L;         // [16][4096][256]
    float* t3  = base + 6291456L;          // [8][4096][512]
    float* t4  = base + 39845888L;         // [4][4096][512]
    float* t5  = base + 23068672L;         // [2][4096][512]

    // ---- pre-split weights (2 frag-ordered planes per level)
    SegTable T;
    auto seg = [](const float* s, long dst, int Z, int G, int Gpad, int K, int tr, int b0) {
        Seg d; d.src=s; d.dst=dst; d.Z=Z; d.G=G; d.Gpad=Gpad; d.K=K; d.trans=tr; d.blk0=b0; return d;
    };
    T.s[0]  = seg(W1,   0L,        1, 128, 128,  64, 1, 0);
    T.s[1]  = seg(W2,   16384L,    1,  64,  64, 128, 1, 4);
    T.s[2]  = seg(W3,   32768L,    1,  32,  32,  64, 1, 8);
    T.s[3]  = seg(W4,   36864L,    1,  32,  32,  32, 1, 9);
    T.s[4]  = seg(P0,   38912L,   64,  64,  64,  32, 0, 10);
    T.s[5]  = seg(P1,   301056L,  32, 128, 128,  64, 0, 74);
    T.s[6]  = seg(P2,   825344L,  16, 256, 256, 128, 0, 202);
    T.s[7]  = seg(P3,   1873920L,  8, 512, 512, 256, 0, 458);
    T.s[8]  = seg(P4,   3971072L,  4, 512, 512, 512, 0, 970);
    T.s[9]  = seg(P5,   6068224L,  2, 512, 512, 512, 0, 1482);
    T.s[10] = seg(Ptop, 7116800L,  1, 1000, 1024, 512, 0, 1738);
    presplit<<<dim3(1994), dim3(256), 0, stream>>>(T, planes);

    dim3 blk(256, 1, 1);

    // ---- MLP + leaf, 2 chunks of 131072 tokens
    for (int c = 0; c < 2; ++c) {
        const float* Xc = X + (long)c * 131072 * 64;
        // mlp1: 64->128 relu   (block 128x128)
        ht_mfma<2, 2, 2, 3, 0><<<dim3(1024, 1, 1), blk, 0, stream>>>(
            Xc, planes + 0, b1, h1c, 64, 128, 4, 0L, 0L, 64, 0L, 128, 1);
        // mlp2: 128->64 relu   (block 128x64)
        ht_mfma<2, 1, 2, 3, 0><<<dim3(1024, 1, 1), blk, 0, stream>>>(
            h1c, planes + 16384, b2, h2c, 128, 64, 2, 0L, 0L, 128, 0L, 64, 1);
        // mlp3: 64->32 relu    (block 256x32)
        ht_mfma<2, 1, 1, 3, 0><<<dim3(512, 1, 1), blk, 0, stream>>>(
            h2c, planes + 32768, b3, h3c, 64, 32, 1, 0L, 0L, 64, 0L, 32, 1);
        // mlp4: 32->32         (block 256x32)
        ht_mfma<2, 1, 1, 3, 0><<<dim3(512, 1, 1), blk, 0, stream>>>(
            h3c, planes + 36864, b4, Fc, 32, 32, 1, 0L, 0L, 32, 0L, 32, 0);
        // leaf: t0[j][b][a] = sum_m P0[j][a][m] * F[(b,j)][m]  (block 128x64)
        ht_mfma<2, 1, 2, 3, 0><<<dim3(16, 1, 64), blk, 0, stream>>>(
            Fc, planes + 38912, nullptr, t0 + (long)c * 131072, 32, 64, 2,
            32L, 0L, 2048, 262144L, 64, 0);
    }

    // ---- tree: t_l[n][b][g] = sum_a P_l[n][g][a] * t[2n][b][a]*t[2n+1][b][a]
    ht_mfma<2, 2, 2, 3, 1><<<dim3(32, 1, 32), blk, 0, stream>>>(   // L1 K=64 G=128
        t0, planes + 301056, nullptr, t1, 64, 128, 4,
        524288L, 262144L, 64, 524288L, 128, 0);
    ht_mfma<2, 4, 2, 2, 1><<<dim3(32, 1, 16), blk, 0, stream>>>(   // L2 K=128 G=256 (128x256)
        t1, planes + 825344, nullptr, t2, 128, 256, 8,
        1048576L, 524288L, 128, 1048576L, 256, 0);
    ht_mfma<2, 4, 2, 2, 1><<<dim3(32, 2, 8), blk, 0, stream>>>(    // L3 K=256 G=512 (128x256)
        t2, planes + 1873920, nullptr, t3, 256, 512, 16,
        2097152L, 1048576L, 256, 2097152L, 512, 0);
    ht_mfma<2, 2, 2, 3, 1><<<dim3(32, 4, 4), blk, 0, stream>>>(    // L4 K=512 G=512 (128x128)
        t3, planes + 3971072, nullptr, t4, 512, 512, 16,
        4194304L, 2097152L, 512, 2097152L, 512, 0);
    ht_mfma<1, 2, 2, 3, 1><<<dim3(64, 4, 2), blk, 0, stream>>>(    // L5 K=512 G=512 (64x128)
        t4, planes + 6068224, nullptr, t5, 512, 512, 16,
        4194304L, 2097152L, 512, 2097152L, 512, 0);
    ht_mfma<1, 2, 2, 3, 1><<<dim3(64, 8, 1), blk, 0, stream>>>(    // top K=512 G=1000 pad1024
        t5, planes + 7116800, nullptr, out, 512, 1000, 32,
        0L, 2097152L, 512, 0L, 1000, 0);
}

// Round 8
// 434.692 us; speedup vs baseline: 2.0047x; 1.1782x over previous
//
#include <hip/hip_runtime.h>

// HT model: exact 2-way bf16 split (x = h + m) + MFMA (v_mfma_f32_32x32x16_bf16,
// products hh', hm', mh', drop mm' ~2^-18), fp32 accumulator.
//
// r8: the whole MLP (64->128->64->32->32) + leaf contraction is ONE fused
// kernel: block = (node j, 64 batch rows); intermediates never touch HBM.
// Each layer: MFMA with W frags read global->VGPR (pre-split frag-ordered
// planes, L2-hot), then bias/relu/split2 and a direct D-reg -> LDS B-frag
// writeback (D col=b == B-frag col=b, so lanes write 8B slots in place).
// Tree levels keep the r7 kernels unchanged. ws >= 185 MB.

typedef short short8 __attribute__((ext_vector_type(8)));
typedef float floatx16 __attribute__((ext_vector_type(16)));

__device__ __forceinline__ unsigned bf16_rne(float x) {
    unsigned u = __float_as_uint(x);
    return (u + 0x7FFFu + ((u >> 16) & 1u)) >> 16;
}
__device__ __forceinline__ float bf16_f(unsigned h) { return __uint_as_float(h << 16); }
__device__ __forceinline__ void split2(float x, unsigned& h, unsigned& m) {
    h = bf16_rne(x);
    float r = x - bf16_f(h);       // exact (Sterbenz)
    m = bf16_rne(r);
}

// ---------------- weight pre-split into fragment-ordered bf16 planes ----------------
// frag = ((z*2+p)*(K/16) + k16)*NGTtot + (g>>5), 512 shorts per frag;
// slot within frag = ((g&31) | ((k8&1)<<5)) * 8 shorts (16B granule).
struct Seg { const float* src; long dst; int Z, G, Gpad, K, trans, blk0; };
struct SegTable { Seg s[11]; };

__global__ __launch_bounds__(256) void presplit(SegTable T, unsigned short* P) {
    int blk = blockIdx.x;
    int si = 0;
#pragma unroll
    for (int i = 1; i < 11; ++i) if (blk >= T.s[i].blk0) si = i;
    Seg d = T.s[si];
    const int K8 = d.K >> 3;
    long total = (long)d.Z * d.Gpad * K8;
    long o = (long)(blk - d.blk0) * 256 + threadIdx.x;
    if (o >= total) return;
    int k8 = (int)(o % K8);
    long rem = o / K8;
    int g = (int)(rem % d.Gpad);
    int z = (int)(rem / d.Gpad);
    float e[8];
    if (g < d.G) {
        if (!d.trans) {
            const float* s = d.src + ((long)z * d.G + g) * d.K + k8 * 8;
            float4 a = *(const float4*)s, b = *(const float4*)(s + 4);
            e[0]=a.x; e[1]=a.y; e[2]=a.z; e[3]=a.w; e[4]=b.x; e[5]=b.y; e[6]=b.z; e[7]=b.w;
        } else {
#pragma unroll
            for (int i = 0; i < 8; ++i) e[i] = d.src[(long)(k8 * 8 + i) * d.G + g];
        }
    } else {
#pragma unroll
        for (int i = 0; i < 8; ++i) e[i] = 0.f;
    }
    unsigned h[8], m[8];
#pragma unroll
    for (int i = 0; i < 8; ++i) split2(e[i], h[i], m[i]);
    uint4 Ph = { h[0]|(h[1]<<16), h[2]|(h[3]<<16), h[4]|(h[5]<<16), h[6]|(h[7]<<16) };
    uint4 Pm = { m[0]|(m[1]<<16), m[2]|(m[3]<<16), m[4]|(m[5]<<16), m[6]|(m[7]<<16) };
    const int NGTt = d.Gpad >> 5;
    const int KC16 = d.K >> 4;
    const long slot = (long)((g & 31) | ((k8 & 1) << 5)) * 8;
    long fh = ((long)(z * 2 + 0) * KC16 + (k8 >> 1)) * NGTt + (g >> 5);
    long fm = ((long)(z * 2 + 1) * KC16 + (k8 >> 1)) * NGTt + (g >> 5);
    *(uint4*)&P[d.dst + fh * 512 + slot] = Ph;
    *(uint4*)&P[d.dst + fm * 512 + slot] = Pm;
}

// ---------------- fused MLP + leaf ----------------
// Block: node j (blockIdx.y), 64 batch rows (blockIdx.x). 4 waves: bw = b-tile,
// gw = g-half. LDS (shorts): [0,8192) X (later h3 [0,4096) + F [4096,8192)),
// [8192,24576) h1, [24576,32768) h2. Total 64 KB -> 2 blocks/CU.
__global__ __launch_bounds__(256, 2) void ht_fused(
    const float* __restrict__ X,
    const unsigned short* __restrict__ Wpl,
    const float* __restrict__ b1, const float* __restrict__ b2,
    const float* __restrict__ b3, const float* __restrict__ b4,
    float* __restrict__ t0)
{
    __shared__ unsigned short AS[32768];
    const int tid  = threadIdx.x;
    const int lane = tid & 63, w = tid >> 6;
    const int bw   = w & 1, gw = w >> 1;
    const int b31  = lane & 31, koct = lane >> 5;
    const int aslot = (b31 * 2 + koct) * 8;
    const int b0 = blockIdx.x * 64;
    const int j  = blockIdx.y;

    // ---- stage X: 64 rows x 64 feats -> 2 planes, 4 kc frags
#pragma unroll
    for (int it = 0; it < 2; ++it) {
        const int s = it * 256 + tid;
        const int b = s >> 3, k8 = s & 7;
        const float* p = X + ((long)(b0 + b) * 64 + j) * 64 + k8 * 8;
        float4 v0 = *(const float4*)p, v1 = *(const float4*)(p + 4);
        float e[8] = { v0.x, v0.y, v0.z, v0.w, v1.x, v1.y, v1.z, v1.w };
        unsigned h[8], m[8];
#pragma unroll
        for (int i = 0; i < 8; ++i) split2(e[i], h[i], m[i]);
        uint4 Ph = { h[0]|(h[1]<<16), h[2]|(h[3]<<16), h[4]|(h[5]<<16), h[6]|(h[7]<<16) };
        uint4 Pm = { m[0]|(m[1]<<16), m[2]|(m[3]<<16), m[4]|(m[5]<<16), m[6]|(m[7]<<16) };
        const int bt = b >> 3 >> 2;          // b>>5
        const int slot = ((b & 31) * 2 + (k8 & 1)) * 8;
        const int kc = k8 >> 1;
        *(uint4*)&AS[((0 * 2 + bt) * 4 + kc) * 512 + slot] = Ph;
        *(uint4*)&AS[((1 * 2 + bt) * 4 + kc) * 512 + slot] = Pm;
    }
    __syncthreads();

    floatx16 acc[2];

    // compute: acc[gt] over ntg g-tiles from LDS src planes + global W planes
    auto comp = [&](int srcbase, int KC, const unsigned short* Wb, int NGTt,
                    int gts, int ntg) {
#pragma unroll
        for (int gt = 0; gt < 2; ++gt) acc[gt] = (floatx16)0.f;
        for (int kc = 0; kc < KC; ++kc) {
            short8 af0 = *(const short8*)&AS[srcbase + ((0 * 2 + bw) * KC + kc) * 512 + aslot];
            short8 af1 = *(const short8*)&AS[srcbase + ((1 * 2 + bw) * KC + kc) * 512 + aslot];
#pragma unroll
            for (int gt = 0; gt < 2; ++gt) {
                if (gt >= ntg) continue;
                const unsigned short* f0 = Wb + ((long)(0 * KC + kc) * NGTt + gts + gt) * 512 + lane * 8;
                const unsigned short* f1 = Wb + ((long)(1 * KC + kc) * NGTt + gts + gt) * 512 + lane * 8;
                short8 w0 = *(const short8*)f0;
                short8 w1 = *(const short8*)f1;
                acc[gt] = __builtin_amdgcn_mfma_f32_32x32x16_bf16(w0, af0, acc[gt], 0, 0, 0);
                acc[gt] = __builtin_amdgcn_mfma_f32_32x32x16_bf16(w0, af1, acc[gt], 0, 0, 0);
                acc[gt] = __builtin_amdgcn_mfma_f32_32x32x16_bf16(w1, af0, acc[gt], 0, 0, 0);
            }
        }
    };

    // writeback: D-regs -> bias/relu -> split2 -> LDS B-frag planes
    auto wb = [&](int ntg, int gts, const float* bias, int relu,
                  int dstbase, int KCd) {
#pragma unroll
        for (int gt = 0; gt < 2; ++gt) {
            if (gt >= ntg) continue;
            const int gtile = gts + gt;
#pragma unroll
            for (int gg = 0; gg < 4; ++gg) {
                float4 bv = make_float4(0.f, 0.f, 0.f, 0.f);
                if (bias) bv = *(const float4*)(bias + gtile * 32 + gg * 8 + koct * 4);
                float o[4] = { acc[gt][gg*4+0] + bv.x, acc[gt][gg*4+1] + bv.y,
                               acc[gt][gg*4+2] + bv.z, acc[gt][gg*4+3] + bv.w };
                if (relu) {
#pragma unroll
                    for (int i = 0; i < 4; ++i) o[i] = fmaxf(o[i], 0.f);
                }
                unsigned h[4], m[4];
#pragma unroll
                for (int i = 0; i < 4; ++i) split2(o[i], h[i], m[i]);
                const int kcd  = gtile * 2 + (gg >> 1);
                const int slot = (b31 * 2 + (gg & 1)) * 8 + koct * 4;
                uint2 ph = { h[0] | (h[1] << 16), h[2] | (h[3] << 16) };
                uint2 pm = { m[0] | (m[1] << 16), m[2] | (m[3] << 16) };
                *(uint2*)&AS[dstbase + ((0 * 2 + bw) * KCd + kcd) * 512 + slot] = ph;
                *(uint2*)&AS[dstbase + ((1 * 2 + bw) * KCd + kcd) * 512 + slot] = pm;
            }
        }
    };

    // L1: X(K=64) -> h1 (G=128), relu
    comp(0, 4, Wpl + 0, 4, gw * 2, 2);
    wb(2, gw * 2, b1, 1, 8192, 8);
    __syncthreads();
    // L2: h1(K=128) -> h2 (G=64), relu
    comp(8192, 8, Wpl + 16384, 2, gw, 1);
    wb(1, gw, b2, 1, 24576, 4);
    __syncthreads();
    // L3: h2(K=64) -> h3 (G=32), relu (gw==0 computes/writes)
    if (gw == 0) {
        comp(24576, 4, Wpl + 32768, 1, 0, 1);
        wb(1, 0, b3, 1, 0, 2);
    }
    __syncthreads();
    // L4: h3(K=32) -> F (G=32)
    if (gw == 0) {
        comp(0, 2, Wpl + 36864, 1, 0, 1);
        wb(1, 0, b4, 0, 4096, 2);
    }
    __syncthreads();
    // leaf: F(K=32) x P0[j] -> t0[j][b][64]
    comp(4096, 2, Wpl + 38912 + (long)j * 4096, 2, gw, 1);
    {
        const int bglob = b0 + bw * 32 + b31;
        float* crow = t0 + (long)j * 262144 + (long)bglob * 64;
#pragma unroll
        for (int gg = 0; gg < 4; ++gg) {
            const int g = gw * 32 + gg * 8 + koct * 4;
            float4 o = make_float4(acc[0][gg*4+0], acc[0][gg*4+1],
                                   acc[0][gg*4+2], acc[0][gg*4+3]);
            *(float4*)(crow + g) = o;
        }
    }
}

// ---------------- tree GEMM (unchanged r7): C[z][b][g] = sum_k W[z][g][k]*Act[z][b][k]
template<int BT, int GTW, int GWAVES, int MINW, int PAIR>
__global__ __launch_bounds__(256, MINW) void ht_mfma(
    const float* __restrict__ Act,
    const unsigned short* __restrict__ Wp,
    const float* __restrict__ bias,
    float* __restrict__ C,
    int K, int Gtot, int NGTtot,
    long act_z, long act_pair, int act_rb,
    long c_z, int c_rb, int relu)
{
    constexpr int BWAVES = 4 / GWAVES;
    constexpr int BB  = BWAVES * BT * 32;
    constexpr int GG  = GWAVES * GTW * 32;
    constexpr int NBT = BB / 32;
    constexpr int NR  = BB / 64;

    __shared__ unsigned short AS[2 * NBT * 1024];

    const int tid  = threadIdx.x;
    const int lane = tid & 63;
    const int w    = tid >> 6;
    const int bw   = w % BWAVES;
    const int gw   = w / BWAVES;

    const int b0  = blockIdx.x * BB;
    const int g0t = blockIdx.y * (GG / 32);
    const int g0  = blockIdx.y * GG;
    const int z   = blockIdx.z;

    const float* Abase = Act + (long)z * act_z + (long)b0 * act_rb;
    const int aslot = ((lane & 31) * 2 + (lane >> 5)) * 8;
    const unsigned short* Wl = Wp + lane * 8;
    const int KC16 = K >> 4;

    auto stage = [&](int k0) {
#pragma unroll
        for (int r = 0; r < NR; ++r) {
            const int s = r * 256 + tid;
            const int b = s >> 2, oct = s & 3;
            const float* p = Abase + (long)b * act_rb + k0 + oct * 8;
            float4 v0 = *(const float4*)p;
            float4 v1 = *(const float4*)(p + 4);
            if (PAIR) {
                float4 u0 = *(const float4*)(p + act_pair);
                float4 u1 = *(const float4*)(p + act_pair + 4);
                v0.x *= u0.x; v0.y *= u0.y; v0.z *= u0.z; v0.w *= u0.w;
                v1.x *= u1.x; v1.y *= u1.y; v1.z *= u1.z; v1.w *= u1.w;
            }
            float e[8] = { v0.x, v0.y, v0.z, v0.w, v1.x, v1.y, v1.z, v1.w };
            unsigned h[8], m[8];
#pragma unroll
            for (int i = 0; i < 8; ++i) split2(e[i], h[i], m[i]);
            uint4 Ph = { h[0]|(h[1]<<16), h[2]|(h[3]<<16), h[4]|(h[5]<<16), h[6]|(h[7]<<16) };
            uint4 Pm = { m[0]|(m[1]<<16), m[2]|(m[3]<<16), m[4]|(m[5]<<16), m[6]|(m[7]<<16) };
            const int base = (b >> 5) * 1024 + (oct >> 1) * 512 + ((b & 31) * 2 + (oct & 1)) * 8;
            *(uint4*)&AS[base] = Ph;
            *(uint4*)&AS[NBT * 1024 + base] = Pm;
        }
    };

    floatx16 acc[BT][GTW];
#pragma unroll
    for (int bt = 0; bt < BT; ++bt)
#pragma unroll
        for (int gt = 0; gt < GTW; ++gt) acc[bt][gt] = (floatx16)0.f;

    stage(0);
    __syncthreads();

    for (int k0 = 0; k0 < K; k0 += 32) {
#pragma unroll
        for (int kc = 0; kc < 2; ++kc) {
            short8 wf[2][GTW];
#pragma unroll
            for (int sa = 0; sa < 2; ++sa)
#pragma unroll
                for (int gt = 0; gt < GTW; ++gt) {
                    const long frag = ((long)(z * 2 + sa) * KC16 + (k0 >> 4) + kc) * NGTtot
                                      + g0t + gw * GTW + gt;
                    wf[sa][gt] = *(const short8*)(Wl + frag * 512);
                }
            short8 af[2][BT];
#pragma unroll
            for (int sb = 0; sb < 2; ++sb)
#pragma unroll
                for (int bt = 0; bt < BT; ++bt)
                    af[sb][bt] = *(const short8*)&AS[(sb * NBT + bw * BT + bt) * 1024
                                                     + kc * 512 + aslot];
#pragma unroll
            for (int gt = 0; gt < GTW; ++gt) {
#pragma unroll
                for (int bt = 0; bt < BT; ++bt)
                    acc[bt][gt] = __builtin_amdgcn_mfma_f32_32x32x16_bf16(
                        wf[0][gt], af[0][bt], acc[bt][gt], 0, 0, 0);
#pragma unroll
                for (int bt = 0; bt < BT; ++bt)
                    acc[bt][gt] = __builtin_amdgcn_mfma_f32_32x32x16_bf16(
                        wf[0][gt], af[1][bt], acc[bt][gt], 0, 0, 0);
#pragma unroll
                for (int bt = 0; bt < BT; ++bt)
                    acc[bt][gt] = __builtin_amdgcn_mfma_f32_32x32x16_bf16(
                        wf[1][gt], af[0][bt], acc[bt][gt], 0, 0, 0);
            }
        }
        if (k0 + 32 < K) {
            __syncthreads();
            stage(k0 + 32);
            __syncthreads();
        }
    }

    const int koct = lane >> 5;
#pragma unroll
    for (int bt = 0; bt < BT; ++bt) {
        const int b = b0 + bw * (BT * 32) + bt * 32 + (lane & 31);
        float* crow = C + (long)z * c_z + (long)b * c_rb;
#pragma unroll
        for (int gt = 0; gt < GTW; ++gt) {
            const int gb = g0 + gw * (GTW * 32) + gt * 32 + 4 * koct;
#pragma unroll
            for (int r4 = 0; r4 < 4; ++r4) {
                const int g = gb + r4 * 8;
                float4 o;
                o.x = acc[bt][gt][r4 * 4 + 0];
                o.y = acc[bt][gt][r4 * 4 + 1];
                o.z = acc[bt][gt][r4 * 4 + 2];
                o.w = acc[bt][gt][r4 * 4 + 3];
                if (bias) {
                    float4 bv = *(const float4*)(bias + g);
                    o.x += bv.x; o.y += bv.y; o.z += bv.z; o.w += bv.w;
                }
                if (relu) {
                    o.x = fmaxf(o.x, 0.f); o.y = fmaxf(o.y, 0.f);
                    o.z = fmaxf(o.z, 0.f); o.w = fmaxf(o.w, 0.f);
                }
                if (g + 3 < Gtot) {
                    *(float4*)(crow + g) = o;
                } else if (g < Gtot) {
                    crow[g] = o.x;
                    if (g + 1 < Gtot) crow[g + 1] = o.y;
                    if (g + 2 < Gtot) crow[g + 2] = o.z;
                }
            }
        }
    }
}

extern "C" void kernel_launch(void* const* d_in, const int* in_sizes, int n_in,
                              void* d_out, int out_size, void* d_ws, size_t ws_size,
                              hipStream_t stream)
{
    const float* X    = (const float*)d_in[0];
    const float* W1   = (const float*)d_in[1];
    const float* b1   = (const float*)d_in[2];
    const float* W2   = (const float*)d_in[3];
    const float* b2   = (const float*)d_in[4];
    const float* W3   = (const float*)d_in[5];
    const float* b3   = (const float*)d_in[6];
    const float* W4   = (const float*)d_in[7];
    const float* b4   = (const float*)d_in[8];
    const float* P0   = (const float*)d_in[9];
    const float* P1   = (const float*)d_in[10];
    const float* P2   = (const float*)d_in[11];
    const float* P3   = (const float*)d_in[12];
    const float* P4   = (const float*)d_in[13];
    const float* P5   = (const float*)d_in[14];
    const float* Ptop = (const float*)d_in[15];
    float* out = (float*)d_out;

    unsigned short* planes = (unsigned short*)d_ws;
    float* base = (float*)d_ws;
    float* t0  = base + 31457280L;         // [64][4096][64]
    float* t1  = base + 6291456L;          // [32][4096][128]
    float* t2  = base + 23068672L;         // [16][4096][256]
    float* t3  = base + 6291456L;          // [8][4096][512]
    float* t4  = base + 39845888L;         // [4][4096][512]
    float* t5  = base + 23068672L;         // [2][4096][512]

    // ---- pre-split weights (2 frag-ordered planes per level)
    SegTable T;
    auto seg = [](const float* s, long dst, int Z, int G, int Gpad, int K, int tr, int b0) {
        Seg d; d.src=s; d.dst=dst; d.Z=Z; d.G=G; d.Gpad=Gpad; d.K=K; d.trans=tr; d.blk0=b0; return d;
    };
    T.s[0]  = seg(W1,   0L,        1, 128, 128,  64, 1, 0);
    T.s[1]  = seg(W2,   16384L,    1,  64,  64, 128, 1, 4);
    T.s[2]  = seg(W3,   32768L,    1,  32,  32,  64, 1, 8);
    T.s[3]  = seg(W4,   36864L,    1,  32,  32,  32, 1, 9);
    T.s[4]  = seg(P0,   38912L,   64,  64,  64,  32, 0, 10);
    T.s[5]  = seg(P1,   301056L,  32, 128, 128,  64, 0, 74);
    T.s[6]  = seg(P2,   825344L,  16, 256, 256, 128, 0, 202);
    T.s[7]  = seg(P3,   1873920L,  8, 512, 512, 256, 0, 458);
    T.s[8]  = seg(P4,   3971072L,  4, 512, 512, 512, 0, 970);
    T.s[9]  = seg(P5,   6068224L,  2, 512, 512, 512, 0, 1482);
    T.s[10] = seg(Ptop, 7116800L,  1, 1000, 1024, 512, 0, 1738);
    presplit<<<dim3(1994), dim3(256), 0, stream>>>(T, planes);

    dim3 blk(256, 1, 1);

    // ---- fused MLP + leaf: one launch, 64 b-tiles x 64 nodes
    ht_fused<<<dim3(64, 64, 1), blk, 0, stream>>>(
        X, planes, b1, b2, b3, b4, t0);

    // ---- tree: t_l[n][b][g] = sum_a P_l[n][g][a] * t[2n][b][a]*t[2n+1][b][a]
    ht_mfma<2, 2, 2, 3, 1><<<dim3(32, 1, 32), blk, 0, stream>>>(   // L1 K=64 G=128
        t0, planes + 301056, nullptr, t1, 64, 128, 4,
        524288L, 262144L, 64, 524288L, 128, 0);
    ht_mfma<2, 4, 2, 2, 1><<<dim3(32, 1, 16), blk, 0, stream>>>(   // L2 K=128 G=256 (128x256)
        t1, planes + 825344, nullptr, t2, 128, 256, 8,
        1048576L, 524288L, 128, 1048576L, 256, 0);
    ht_mfma<2, 4, 2, 2, 1><<<dim3(32, 2, 8), blk, 0, stream>>>(    // L3 K=256 G=512 (128x256)
        t2, planes + 1873920, nullptr, t3, 256, 512, 16,
        2097152L, 1048576L, 256, 2097152L, 512, 0);
    ht_mfma<2, 2, 2, 3, 1><<<dim3(32, 4, 4), blk, 0, stream>>>(    // L4 K=512 G=512 (128x128)
        t3, planes + 3971072, nullptr, t4, 512, 512, 16,
        4194304L, 2097152L, 512, 2097152L, 512, 0);
    ht_mfma<1, 2, 2, 3, 1><<<dim3(64, 4, 2), blk, 0, stream>>>(    // L5 K=512 G=512 (64x128)
        t4, planes + 6068224, nullptr, t5, 512, 512, 16,
        4194304L, 2097152L, 512, 2097152L, 512, 0);
    ht_mfma<1, 2, 2, 3, 1><<<dim3(64, 8, 1), blk, 0, stream>>>(    // top K=512 G=1000 pad1024
        t5, planes + 7116800, nullptr, out, 512, 1000, 32,
        0L, 2097152L, 512, 0L, 1000, 0);
}